// Round 6
// baseline (28.553 us; speedup 1.0000x reference)
//
#include <hip/hip_runtime.h>
#include <hip/hip_bf16.h>
#include <math.h>

#define NB_TASKS 20
#define CLASSES_PER_TASK 100
#define N_COLS (NB_TASKS * CLASSES_PER_TASK)   // 2000
#define N_F4   (N_COLS / 4)                    // 500
#define F4_PER_TASK (CLASSES_PER_TASK / 4)     // 25
#define INV_TEMP (1.0f / 5.0f)
#define ROWS_PER_BLOCK 4

typedef float vf4 __attribute__((ext_vector_type(4)));  // NT-store-compatible

__device__ __forceinline__ float rfl_f(float x) {
    return __int_as_float(__builtin_amdgcn_readfirstlane(__float_as_int(x)));
}

struct Top2 { int j1, j2; float w1, w2; };

// v: lane t (t<20) holds value for task t; lanes 20..63 hold -INF.
// Returns wave-uniform top-2 indices and softmax weights (scaled by coef).
__device__ __forceinline__ Top2 softmax_top2(float v, float coef, int lane) {
    // argmax, min-index tiebreak (== jax top_k tie rule); data lives in lanes 0..31
    float v1 = v; int i1 = lane;
    #pragma unroll
    for (int off = 16; off; off >>= 1) {
        float ov = __shfl_xor(v1, off);
        int   oj = __shfl_xor(i1, off);
        if (ov > v1 || (ov == v1 && oj < i1)) { v1 = ov; i1 = oj; }
    }
    // second argmax, excluding lane i1
    float v2 = (lane == i1) ? -INFINITY : v;
    int   i2 = lane;
    #pragma unroll
    for (int off = 16; off; off >>= 1) {
        float ov = __shfl_xor(v2, off);
        int   oj = __shfl_xor(i2, off);
        if (ov > v2 || (ov == v2 && oj < i2)) { v2 = ov; i2 = oj; }
    }
    // softmax denominator: exp((v - max)/T); -INF lanes contribute 0
    float ex  = __expf((v - v1) * INV_TEMP);
    float sum = ex;
    #pragma unroll
    for (int off = 16; off; off >>= 1)
        sum += __shfl_xor(sum, off);

    Top2 r;
    r.j1 = __builtin_amdgcn_readfirstlane(i1);
    r.j2 = __builtin_amdgcn_readfirstlane(i2);
    float w1 = coef / sum;                        // exp(0) = 1
    float w2 = __expf((v2 - v1) * INV_TEMP) * w1;
    r.w1 = rfl_f(w1);
    r.w2 = rfl_f(w2);
    return r;
}

__global__ __launch_bounds__(256) void mix_kernel(
    const float* __restrict__ gol,     // [B, 20]
    const float* __restrict__ gocls,   // [B, 2000]
    const float* __restrict__ dol,     // [B, 2000]
    const float* __restrict__ alpha_p, // [1]
    float* __restrict__ out,           // [B, 2000]
    int B)
{
    const int tid  = threadIdx.x;
    const int lane = tid & 63;
    const int b    = blockIdx.x * ROWS_PER_BLOCK + (tid >> 6);
    if (b >= B) return;

    const int grp = lane >> 4;   // 16-lane group: 0..3
    const int s   = lane & 15;

    const vf4*   din  = (const vf4*)(dol + (size_t)b * N_COLS);
    vf4*         dout = (vf4*)(out + (size_t)b * N_COLS);
    const float* grow = gocls + (size_t)b * N_COLS;

    // --- path A (gol): depends only on an 80B load -> resolve FIRST ---
    const float a  = alpha_p[0];
    const float gv = (lane < NB_TASKS) ? gol[(size_t)b * NB_TASKS + lane] : -INFINITY;
    const Top2 pa = softmax_top2(gv, a, lane);

    // issue dol loads for A-tasks now; latency hidden under the gocls reduce
    vf4 dA1 = {0,0,0,0}, dA2 = {0,0,0,0};
    if (lane < F4_PER_TASK) {
        dA1 = din[pa.j1 * F4_PER_TASK + lane];
        dA2 = din[pa.j2 * F4_PER_TASK + lane];
    }

    // --- zero-blast the 18 non-A task regions (NT: don't evict L3-resident
    //     inputs). Depends only on pa -> overlaps the whole gocls reduce. ---
    {
        const vf4 z = {0.0f, 0.0f, 0.0f, 0.0f};
        #pragma unroll
        for (int i = 0; i < (N_F4 + 63) / 64; ++i) {
            const int f = lane + 64 * i;
            if (f < N_F4) {
                const int task = f / F4_PER_TASK;
                if (task != pa.j1 && task != pa.j2)
                    __builtin_nontemporal_store(z, &dout[f]);
            }
        }
    }

    // --- per-task max over 100 classes, 4 tasks per iteration ---
    float cv = -INFINITY;
    #pragma unroll
    for (int k = 0; k < 5; ++k) {
        const vf4* p = (const vf4*)(grow + (4 * k + grp) * CLASSES_PER_TASK);
        vf4 v0 = p[s];
        float m = fmaxf(fmaxf(v0.x, v0.y), fmaxf(v0.z, v0.w));
        if (s < 25 - 16) {
            vf4 v1 = p[16 + s];
            m = fmaxf(m, fmaxf(fmaxf(v1.x, v1.y), fmaxf(v1.z, v1.w)));
        }
        #pragma unroll
        for (int off = 8; off; off >>= 1)          // butterfly within 16-lane group
            m = fmaxf(m, __shfl_xor(m, off));
        float g2 = __shfl(m, (lane & 3) << 4);     // lane 4k+g <- group g's max
        if ((lane >> 2) == k) cv = g2;             // lanes 0..19 collect task maxes
    }

    // --- path B (per-task gocls max) ---
    const Top2 pb = softmax_top2(cv, 1.0f - a, lane);

    // fold B weights into A where indices coincide
    const float wA1 = pa.w1 + ((pb.j1 == pa.j1) ? pb.w1 : 0.0f)
                            + ((pb.j2 == pa.j1) ? pb.w2 : 0.0f);
    const float wA2 = pa.w2 + ((pb.j1 == pa.j2) ? pb.w1 : 0.0f)
                            + ((pb.j2 == pa.j2) ? pb.w2 : 0.0f);
    const bool bo1 = (pb.j1 != pa.j1) && (pb.j1 != pa.j2);
    const bool bo2 = (pb.j2 != pa.j1) && (pb.j2 != pa.j2);

    // issue B-only dol loads before anything else in the tail
    vf4 dB1 = {0,0,0,0}, dB2 = {0,0,0,0};
    if (lane < F4_PER_TASK) {
        if (bo1) dB1 = din[pb.j1 * F4_PER_TASK + lane];
        if (bo2) dB2 = din[pb.j2 * F4_PER_TASK + lane];

        // A-task regions were never zero-blasted: single write, no fence needed
        __builtin_nontemporal_store(dA1 * wA1, &dout[pa.j1 * F4_PER_TASK + lane]);
        __builtin_nontemporal_store(dA2 * wA2, &dout[pa.j2 * F4_PER_TASK + lane]);
    }

    // B-only regions WERE zero-blasted: make sure zeros landed before overwrite
    asm volatile("s_waitcnt vmcnt(0)" ::: "memory");

    if (lane < F4_PER_TASK) {
        if (bo1) __builtin_nontemporal_store(dB1 * pb.w1, &dout[pb.j1 * F4_PER_TASK + lane]);
        if (bo2) __builtin_nontemporal_store(dB2 * pb.w2, &dout[pb.j2 * F4_PER_TASK + lane]);
    }
}

extern "C" void kernel_launch(void* const* d_in, const int* in_sizes, int n_in,
                              void* d_out, int out_size, void* d_ws, size_t ws_size,
                              hipStream_t stream) {
    const float* gol   = (const float*)d_in[0];
    const float* gocls = (const float*)d_in[1];
    const float* dol   = (const float*)d_in[2];
    const float* alpha = (const float*)d_in[3];
    float* out = (float*)d_out;

    const int B = in_sizes[0] / NB_TASKS;  // 8192

    const int grid = (B + ROWS_PER_BLOCK - 1) / ROWS_PER_BLOCK;
    hipLaunchKernelGGL(mix_kernel, dim3(grid), dim3(256), 0, stream,
                       gol, gocls, dol, alpha, out, B);
}

// Round 7
// 28.264 us; speedup vs baseline: 1.0102x; 1.0102x over previous
//
#include <hip/hip_runtime.h>
#include <hip/hip_bf16.h>
#include <math.h>

#define NB_TASKS 20
#define CLASSES_PER_TASK 100
#define N_COLS (NB_TASKS * CLASSES_PER_TASK)   // 2000
#define N_F4   (N_COLS / 4)                    // 500
#define F4_PER_TASK (CLASSES_PER_TASK / 4)     // 25
#define INV_TEMP (1.0f / 5.0f)
#define ROWS_PER_BLOCK 4

typedef float vf4 __attribute__((ext_vector_type(4)));

__device__ __forceinline__ float rfl_f(float x) {
    return __int_as_float(__builtin_amdgcn_readfirstlane(__float_as_int(x)));
}

struct Top2 { int j1, j2; float w1, w2; };

// v: lane t (t<20) holds value for task t; lanes 20..63 hold -INF.
// Returns wave-uniform top-2 indices and softmax weights (scaled by coef).
__device__ __forceinline__ Top2 softmax_top2(float v, float coef, int lane) {
    // argmax, min-index tiebreak (== jax top_k tie rule); data lives in lanes 0..31
    float v1 = v; int i1 = lane;
    #pragma unroll
    for (int off = 16; off; off >>= 1) {
        float ov = __shfl_xor(v1, off);
        int   oj = __shfl_xor(i1, off);
        if (ov > v1 || (ov == v1 && oj < i1)) { v1 = ov; i1 = oj; }
    }
    // second argmax, excluding lane i1
    float v2 = (lane == i1) ? -INFINITY : v;
    int   i2 = lane;
    #pragma unroll
    for (int off = 16; off; off >>= 1) {
        float ov = __shfl_xor(v2, off);
        int   oj = __shfl_xor(i2, off);
        if (ov > v2 || (ov == v2 && oj < i2)) { v2 = ov; i2 = oj; }
    }
    // softmax denominator: exp((v - max)/T); -INF lanes contribute 0
    float ex  = __expf((v - v1) * INV_TEMP);
    float sum = ex;
    #pragma unroll
    for (int off = 16; off; off >>= 1)
        sum += __shfl_xor(sum, off);

    Top2 r;
    r.j1 = __builtin_amdgcn_readfirstlane(i1);
    r.j2 = __builtin_amdgcn_readfirstlane(i2);
    float w1 = coef / sum;                        // exp(0) = 1
    float w2 = __expf((v2 - v1) * INV_TEMP) * w1;
    r.w1 = rfl_f(w1);
    r.w2 = rfl_f(w2);
    return r;
}

__global__ __launch_bounds__(256) void mix_kernel(
    const float* __restrict__ gol,     // [B, 20]
    const float* __restrict__ gocls,   // [B, 2000]
    const float* __restrict__ dol,     // [B, 2000]
    const float* __restrict__ alpha_p, // [1]
    float* __restrict__ out,           // [B, 2000]
    int B)
{
    const int tid  = threadIdx.x;
    const int lane = tid & 63;
    const int b    = blockIdx.x * ROWS_PER_BLOCK + (tid >> 6);
    if (b >= B) return;

    // phase stagger: even blocks write zeros early (mixing with odd blocks'
    // reads); odd blocks read first and write everything exactly once late.
    const bool early = (blockIdx.x & 1) == 0;

    const int grp = lane >> 4;   // 16-lane group: 0..3
    const int s   = lane & 15;

    const vf4*   din  = (const vf4*)(dol + (size_t)b * N_COLS);
    vf4*         dout = (vf4*)(out + (size_t)b * N_COLS);
    const float* grow = gocls + (size_t)b * N_COLS;

    // --- path A (gol): depends only on an 80B load -> resolve FIRST ---
    const float a  = alpha_p[0];
    const float gv = (lane < NB_TASKS) ? gol[(size_t)b * NB_TASKS + lane] : -INFINITY;
    const Top2 pa = softmax_top2(gv, a, lane);

    // issue dol loads for A-tasks now; latency hidden under the gocls reduce
    vf4 dA1 = {0,0,0,0}, dA2 = {0,0,0,0};
    if (lane < F4_PER_TASK) {
        dA1 = din[pa.j1 * F4_PER_TASK + lane];
        dA2 = din[pa.j2 * F4_PER_TASK + lane];
    }

    // --- even blocks: zero-blast the 18 non-A task regions NOW (overlaps the
    //     reduce; 2 B-regions may be rewritten later -> fence before tail) ---
    if (early) {
        const vf4 z = {0.0f, 0.0f, 0.0f, 0.0f};
        #pragma unroll
        for (int i = 0; i < (N_F4 + 63) / 64; ++i) {
            const int f = lane + 64 * i;
            if (f < N_F4) {
                const int task = f / F4_PER_TASK;
                if (task != pa.j1 && task != pa.j2)
                    __builtin_nontemporal_store(z, &dout[f]);
            }
        }
    }

    // --- per-task max over 100 classes, 4 tasks per iteration ---
    float cv = -INFINITY;
    #pragma unroll
    for (int k = 0; k < 5; ++k) {
        const vf4* p = (const vf4*)(grow + (4 * k + grp) * CLASSES_PER_TASK);
        vf4 v0 = p[s];
        float m = fmaxf(fmaxf(v0.x, v0.y), fmaxf(v0.z, v0.w));
        if (s < 25 - 16) {
            vf4 v1 = p[16 + s];
            m = fmaxf(m, fmaxf(fmaxf(v1.x, v1.y), fmaxf(v1.z, v1.w)));
        }
        #pragma unroll
        for (int off = 8; off; off >>= 1)          // butterfly within 16-lane group
            m = fmaxf(m, __shfl_xor(m, off));
        float g2 = __shfl(m, (lane & 3) << 4);     // lane 4k+g <- group g's max
        if ((lane >> 2) == k) cv = g2;             // lanes 0..19 collect task maxes
    }

    // --- path B (per-task gocls max) ---
    const Top2 pb = softmax_top2(cv, 1.0f - a, lane);

    // fold B weights into A where indices coincide
    const float wA1 = pa.w1 + ((pb.j1 == pa.j1) ? pb.w1 : 0.0f)
                            + ((pb.j2 == pa.j1) ? pb.w2 : 0.0f);
    const float wA2 = pa.w2 + ((pb.j1 == pa.j2) ? pb.w1 : 0.0f)
                            + ((pb.j2 == pa.j2) ? pb.w2 : 0.0f);
    const bool bo1 = (pb.j1 != pa.j1) && (pb.j1 != pa.j2);
    const bool bo2 = (pb.j2 != pa.j1) && (pb.j2 != pa.j2);

    // issue B-only dol loads before the tail stores
    vf4 dB1 = {0,0,0,0}, dB2 = {0,0,0,0};
    if (lane < F4_PER_TASK) {
        if (bo1) dB1 = din[pb.j1 * F4_PER_TASK + lane];
        if (bo2) dB2 = din[pb.j2 * F4_PER_TASK + lane];
    }

    if (early) {
        // A-regions were never blasted: single write, no ordering hazard
        if (lane < F4_PER_TASK) {
            __builtin_nontemporal_store(dA1 * wA1, &dout[pa.j1 * F4_PER_TASK + lane]);
            __builtin_nontemporal_store(dA2 * wA2, &dout[pa.j2 * F4_PER_TASK + lane]);
        }
        // B-only regions were zero-blasted: zeros must land before overwrite
        asm volatile("s_waitcnt vmcnt(0)" ::: "memory");
        if (lane < F4_PER_TASK) {
            if (bo1) __builtin_nontemporal_store(dB1 * pb.w1, &dout[pb.j1 * F4_PER_TASK + lane]);
            if (bo2) __builtin_nontemporal_store(dB2 * pb.w2, &dout[pb.j2 * F4_PER_TASK + lane]);
        }
    } else {
        // exact single-write: zero only non-topk regions, then the 4 regions
        const vf4 z = {0.0f, 0.0f, 0.0f, 0.0f};
        #pragma unroll
        for (int i = 0; i < (N_F4 + 63) / 64; ++i) {
            const int f = lane + 64 * i;
            if (f < N_F4) {
                const int task = f / F4_PER_TASK;
                if (task != pa.j1 && task != pa.j2 &&
                    task != pb.j1 && task != pb.j2)
                    __builtin_nontemporal_store(z, &dout[f]);
            }
        }
        if (lane < F4_PER_TASK) {
            __builtin_nontemporal_store(dA1 * wA1, &dout[pa.j1 * F4_PER_TASK + lane]);
            __builtin_nontemporal_store(dA2 * wA2, &dout[pa.j2 * F4_PER_TASK + lane]);
            if (bo1) __builtin_nontemporal_store(dB1 * pb.w1, &dout[pb.j1 * F4_PER_TASK + lane]);
            if (bo2) __builtin_nontemporal_store(dB2 * pb.w2, &dout[pb.j2 * F4_PER_TASK + lane]);
        }
    }
}

extern "C" void kernel_launch(void* const* d_in, const int* in_sizes, int n_in,
                              void* d_out, int out_size, void* d_ws, size_t ws_size,
                              hipStream_t stream) {
    const float* gol   = (const float*)d_in[0];
    const float* gocls = (const float*)d_in[1];
    const float* dol   = (const float*)d_in[2];
    const float* alpha = (const float*)d_in[3];
    float* out = (float*)d_out;

    const int B = in_sizes[0] / NB_TASKS;  // 8192

    const int grid = (B + ROWS_PER_BLOCK - 1) / ROWS_PER_BLOCK;
    hipLaunchKernelGGL(mix_kernel, dim3(grid), dim3(256), 0, stream,
                       gol, gocls, dol, alpha, out, B);
}